// Round 10
// baseline (116.324 us; speedup 1.0000x reference)
//
#include <hip/hip_runtime.h>

constexpr int POOL  = 7;
constexpr int GRIDS = 2;
constexpr float SCALE = 0.0625f;
constexpr int N_IMG = 4, C = 490, H = 100, W = 100;
constexpr int PLANE = H * W;                 // 10000 floats = 40 KB
constexpr int N16   = PLANE / 4;             // 2500 16-byte lane-transfers/plane
constexpr int NTHR  = 1024;                  // 16 waves
constexpr int NWAVE = NTHR / 64;
constexpr int MAX_IT = 2;                    // K <= NTHR*MAX_IT handled here

// ---- kernel: one block per c_in; ALL 4 images' planes staged in 160 KB LDS.
// At the per-CU global_load_lds streaming floor (78.4 MB total, ~13.5 us).
__global__ __launch_bounds__(NTHR) void psroi_lds4_kernel(
    const float* __restrict__ x, const float* __restrict__ rois,
    float* __restrict__ wsbuf, int K)
{
    __shared__ float plane4[N_IMG * PLANE];  // 160000 B (gfx950 LDS = 163840 B)
    int c_in = blockIdx.x;

    int lane = threadIdx.x & 63;
    int wave = threadIdx.x >> 6;

#pragma unroll
    for (int img = 0; img < N_IMG; ++img) {
        const float* src = x + ((size_t)img * C + c_in) * PLANE;
        float* dstbase = plane4 + img * PLANE;
        for (int chunk = wave; chunk * 64 < N16; chunk += NWAVE) {
            int t16 = chunk * 64 + lane;
            if (t16 < N16) {
                __builtin_amdgcn_global_load_lds(
                    (const __attribute__((address_space(1))) void*)(src + t16 * 4),
                    (__attribute__((address_space(3))) void*)(dstbase + chunk * 256),
                    16, 0, 0);
            }
        }
    }

    // prefetch my ROI records while the DMA streams (no LDS dependence)
    float rp[MAX_IT][5];
    int nit = 0;
    for (int k = threadIdx.x; k < K && nit < MAX_IT; k += NTHR, ++nit) {
        const float* roi = rois + (size_t)k * 5;
        rp[nit][0] = roi[0]; rp[nit][1] = roi[1]; rp[nit][2] = roi[2];
        rp[nit][3] = roi[3]; rp[nit][4] = roi[4];
    }

    __syncthreads();   // drains vmcnt for LDS-bound loads

    int ph = (c_in / POOL) % POOL;           // block-uniform
    int pw = c_in % POOL;

    for (int it = 0; it < nit; ++it) {
        int k = threadIdx.x + it * NTHR;
        int   img = (int)rp[it][0];
        float rx1 = rp[it][1] * SCALE - 0.5f;
        float ry1 = rp[it][2] * SCALE - 0.5f;
        float rx2 = rp[it][3] * SCALE - 0.5f;
        float ry2 = rp[it][4] * SCALE - 0.5f;
        float bsh = (ry2 - ry1) * (1.0f / POOL);
        float bsw = (rx2 - rx1) * (1.0f / POOL);
        const float* pl = plane4 + img * PLANE;   // per-lane LDS base

        int   rowlo[GRIDS], rowhi[GRIDS];
        float wyl[GRIDS], wyh[GRIDS];
        bool  vy[GRIDS];
        int   xlo[GRIDS], xhi[GRIDS];
        float wxl[GRIDS], wxh[GRIDS];
        bool  vx[GRIDS];
#pragma unroll
        for (int g = 0; g < GRIDS; ++g) {
            float yy = ry1 + ((float)ph + ((float)g + 0.5f) * (1.0f / GRIDS)) * bsh;
            vy[g] = (yy >= -1.0f) && (yy <= (float)H);
            float yc = fmaxf(yy, 0.0f);
            int lo = min((int)yc, H - 1);
            rowlo[g] = lo * W;
            rowhi[g] = min(lo + 1, H - 1) * W;
            float fy = (lo >= H - 1) ? 0.0f : (yc - (float)lo);
            wyl[g] = 1.0f - fy;  wyh[g] = fy;

            float xxv = rx1 + ((float)pw + ((float)g + 0.5f) * (1.0f / GRIDS)) * bsw;
            vx[g] = (xxv >= -1.0f) && (xxv <= (float)W);
            float xc = fmaxf(xxv, 0.0f);
            int lo2 = min((int)xc, W - 1);
            xlo[g] = lo2;
            xhi[g] = min(lo2 + 1, W - 1);
            float fx = (lo2 >= W - 1) ? 0.0f : (xc - (float)lo2);
            wxl[g] = 1.0f - fx;  wxh[g] = fx;
        }

        float acc = 0.0f;
#pragma unroll
        for (int gy = 0; gy < GRIDS; ++gy) {
#pragma unroll
            for (int gx = 0; gx < GRIDS; ++gx) {
                float v0 = pl[rowlo[gy] + xlo[gx]];
                float v1 = pl[rowlo[gy] + xhi[gx]];
                float v2 = pl[rowhi[gy] + xlo[gx]];
                float v3 = pl[rowhi[gy] + xhi[gx]];
                float w = (vy[gy] && vx[gx]) ? 0.25f : 0.0f;
                acc += w * (wyl[gy] * (wxl[gx] * v0 + wxh[gx] * v1)
                          + wyh[gy] * (wxl[gx] * v2 + wxh[gx] * v3));
            }
        }
        wsbuf[c_in * K + k] = acc;   // coalesced
    }
}

// ---- 64x64-tile transpose, float4 on BOTH global sides, 256 blocks (1/CU).
// ws[c*K+k] -> out[k*C+c].  Requires K % 64 == 0; C edge guarded.
__global__ __launch_bounds__(256) void transpose64_kernel(
    const float* __restrict__ wsbuf, float* __restrict__ out, int K)
{
    __shared__ float tile[64][65];           // +1 pad: write-phase reads are 2-way max
    int nkb = K >> 6;                        // K/64 tiles along k
    int cb  = blockIdx.x / nkb;              // 8 tiles along c (8*64=512 >= 490)
    int kb  = blockIdx.x % nkb;
    int c0 = cb * 64, k0 = kb * 64;

    // load: thread t -> float4 along k.  kq = t%16, cr = t/16 (+16 step)
    int kq = (threadIdx.x & 15) * 4;
    int cr = threadIdx.x >> 4;               // 0..15
#pragma unroll
    for (int s = 0; s < 4; ++s) {
        int c = c0 + cr + s * 16;
        float4 v;
        if (c < C) v = *(const float4*)(wsbuf + (size_t)c * K + k0 + kq);
        else       v = make_float4(0.f, 0.f, 0.f, 0.f);
        int r = cr + s * 16;
        tile[r][kq + 0] = v.x; tile[r][kq + 1] = v.y;
        tile[r][kq + 2] = v.z; tile[r][kq + 3] = v.w;
    }
    __syncthreads();

    // store: thread t -> float4 along c.  cq = t%16, kr = t/16 (+16 step)
    int cq = (threadIdx.x & 15) * 4;
    int kr = threadIdx.x >> 4;
#pragma unroll
    for (int s = 0; s < 4; ++s) {
        int k = k0 + kr + s * 16;
        int c = c0 + cq;
        float4 v;
        v.x = tile[cq + 0][kr + s * 16];
        v.y = tile[cq + 1][kr + s * 16];
        v.z = tile[cq + 2][kr + s * 16];
        v.w = tile[cq + 3][kr + s * 16];
        if (c + 3 < C) {
            *(float4*)(out + (size_t)k * C + c) = v;
        } else {                              // ragged C edge (c0=448 tile)
            if (c + 0 < C) out[(size_t)k * C + c + 0] = v.x;
            if (c + 1 < C) out[(size_t)k * C + c + 1] = v.y;
            if (c + 2 < C) out[(size_t)k * C + c + 2] = v.z;
            if (c + 3 < C) out[(size_t)k * C + c + 3] = v.w;
        }
    }
}

// ------------- fallback: direct-store kernel -------------
__global__ __launch_bounds__(256) void psroi_direct_kernel(
    const float* __restrict__ x, const float* __restrict__ rois,
    float* __restrict__ out, int K, int numKC)
{
    int bid  = blockIdx.x;
    int c_lo = bid & 7;
    int t    = bid >> 3;
    int kc   = t % numKC;
    int c_hi = t / numKC;
    int c_in = c_hi * 8 + c_lo;
    if (c_in >= C) return;
    int k = kc * 256 + (int)threadIdx.x;
    if (k >= K) return;

    int ph = (c_in / POOL) % POOL;
    int pw = c_in % POOL;
    const float* roi = rois + (size_t)k * 5;
    int   img = (int)roi[0];
    float rx1 = roi[1] * SCALE - 0.5f;
    float ry1 = roi[2] * SCALE - 0.5f;
    float rx2 = roi[3] * SCALE - 0.5f;
    float ry2 = roi[4] * SCALE - 0.5f;
    float bsh = (ry2 - ry1) * (1.0f / POOL);
    float bsw = (rx2 - rx1) * (1.0f / POOL);
    int off0 = (img * C + c_in) * PLANE;

    float acc = 0.0f;
#pragma unroll
    for (int gy = 0; gy < GRIDS; ++gy) {
        float yy = ry1 + ((float)ph + ((float)gy + 0.5f) * (1.0f / GRIDS)) * bsh;
        bool vy = (yy >= -1.0f) && (yy <= (float)H);
        float yc = fmaxf(yy, 0.0f);
        int lo = min((int)yc, H - 1);
        int rl = lo * W, rh = min(lo + 1, H - 1) * W;
        float fy = (lo >= H - 1) ? 0.0f : (yc - (float)lo);
#pragma unroll
        for (int gx = 0; gx < GRIDS; ++gx) {
            float xxv = rx1 + ((float)pw + ((float)gx + 0.5f) * (1.0f / GRIDS)) * bsw;
            bool vx = (xxv >= -1.0f) && (xxv <= (float)W);
            float xc = fmaxf(xxv, 0.0f);
            int lo2 = min((int)xc, W - 1);
            int xh = min(lo2 + 1, W - 1);
            float fx = (lo2 >= W - 1) ? 0.0f : (xc - (float)lo2);
            float w = (vy && vx) ? 0.25f : 0.0f;
            acc += w * ((1.0f - fy) * ((1.0f - fx) * x[off0 + rl + lo2] + fx * x[off0 + rl + xh])
                      + fy          * ((1.0f - fx) * x[off0 + rh + lo2] + fx * x[off0 + rh + xh]));
        }
    }
    out[k * C + c_in] = acc;
}

extern "C" void kernel_launch(void* const* d_in, const int* in_sizes, int n_in,
                              void* d_out, int out_size, void* d_ws, size_t ws_size,
                              hipStream_t stream) {
    const float* x    = (const float*)d_in[0];
    const float* rois = (const float*)d_in[1];
    float* out = (float*)d_out;
    int K = in_sizes[1] / 5;                              // 2048

    size_t wsbuf_bytes = (size_t)C * K * sizeof(float);   // 4,014,080

    if (ws_size >= wsbuf_bytes && (K % 64) == 0 && K <= NTHR * MAX_IT) {
        float* wsbuf = (float*)d_ws;
        psroi_lds4_kernel<<<C, NTHR, 0, stream>>>(x, rois, wsbuf, K);
        transpose64_kernel<<<8 * (K / 64), 256, 0, stream>>>(wsbuf, out, K);
    } else {
        int numKC = (K + 255) / 256;
        int blocks = ((C + 7) / 8) * numKC * 8;
        psroi_direct_kernel<<<blocks, 256, 0, stream>>>(x, rois, out, K, numKC);
    }
}

// Round 11
// 111.943 us; speedup vs baseline: 1.0391x; 1.0391x over previous
//
#include <hip/hip_runtime.h>

constexpr int POOL  = 7;
constexpr int GRIDS = 2;
constexpr float SCALE = 0.0625f;
constexpr int N_IMG = 4, C = 490, H = 100, W = 100;
constexpr int PLANE = H * W;                 // 10000 floats = 40 KB
constexpr int N16   = PLANE / 4;             // 2500 16-byte lane-transfers/plane
constexpr int NTHR  = 1024;                  // 16 waves
constexpr int NWAVE = NTHR / 64;
constexpr int MAX_IT = 2;                    // K <= NTHR*MAX_IT handled here

// ---- compute kernel: block = (c_in, img-pair p). 2 planes (80 KB) in LDS ->
// 2 blocks/CU co-resident: next block's global_load_lds DMA overlaps this
// block's LDS-gather compute (R9's 160KB variant serialized them).
// Lanes whose ROI image is outside the pair are exec-masked (no partition
// kernel). Pair partners share blockIdx%8 -> same XCD -> ws line writes merge.
__global__ __launch_bounds__(NTHR) void psroi_pair_kernel(
    const float* __restrict__ x, const float* __restrict__ rois,
    float* __restrict__ wsbuf, int K)
{
    __shared__ float plane2[2 * PLANE];      // 80000 B
    int bid  = blockIdx.x;
    int c_lo = bid & 7;
    int rest = bid >> 3;
    int p    = rest & 1;                     // image pair: {2p, 2p+1}
    int c_hi = rest >> 1;
    int c_in = c_hi * 8 + c_lo;
    if (c_in >= C) return;

    int lane = threadIdx.x & 63;
    int wave = threadIdx.x >> 6;

    // stage the pair's two planes via async global_load_lds width=16
#pragma unroll
    for (int i = 0; i < 2; ++i) {
        const float* src = x + ((size_t)(2 * p + i) * C + c_in) * PLANE;
        float* dstbase = plane2 + i * PLANE;
        for (int chunk = wave; chunk * 64 < N16; chunk += NWAVE) {
            int t16 = chunk * 64 + lane;
            if (t16 < N16) {
                __builtin_amdgcn_global_load_lds(
                    (const __attribute__((address_space(1))) void*)(src + t16 * 4),
                    (__attribute__((address_space(3))) void*)(dstbase + chunk * 256),
                    16, 0, 0);
            }
        }
    }

    // prefetch my ROI records while the DMA streams (no LDS dependence)
    float rp[MAX_IT][5];
    int nit = 0;
    for (int k = threadIdx.x; k < K && nit < MAX_IT; k += NTHR, ++nit) {
        const float* roi = rois + (size_t)k * 5;
        rp[nit][0] = roi[0]; rp[nit][1] = roi[1]; rp[nit][2] = roi[2];
        rp[nit][3] = roi[3]; rp[nit][4] = roi[4];
    }

    __syncthreads();   // drains vmcnt for LDS-bound loads

    int ph = (c_in / POOL) % POOL;           // block-uniform
    int pw = c_in % POOL;

    for (int it = 0; it < nit; ++it) {
        int k = threadIdx.x + it * NTHR;
        int img = (int)rp[it][0];
        if ((img >> 1) != p) continue;       // exec-masked; other pair-block handles it

        float rx1 = rp[it][1] * SCALE - 0.5f;
        float ry1 = rp[it][2] * SCALE - 0.5f;
        float rx2 = rp[it][3] * SCALE - 0.5f;
        float ry2 = rp[it][4] * SCALE - 0.5f;
        float bsh = (ry2 - ry1) * (1.0f / POOL);
        float bsw = (rx2 - rx1) * (1.0f / POOL);
        const float* pl = plane2 + (img & 1) * PLANE;

        int   rowlo[GRIDS], rowhi[GRIDS];
        float wyl[GRIDS], wyh[GRIDS];
        bool  vy[GRIDS];
        int   xlo[GRIDS], xhi[GRIDS];
        float wxl[GRIDS], wxh[GRIDS];
        bool  vx[GRIDS];
#pragma unroll
        for (int g = 0; g < GRIDS; ++g) {
            float yy = ry1 + ((float)ph + ((float)g + 0.5f) * (1.0f / GRIDS)) * bsh;
            vy[g] = (yy >= -1.0f) && (yy <= (float)H);
            float yc = fmaxf(yy, 0.0f);
            int lo = min((int)yc, H - 1);
            rowlo[g] = lo * W;
            rowhi[g] = min(lo + 1, H - 1) * W;
            float fy = (lo >= H - 1) ? 0.0f : (yc - (float)lo);
            wyl[g] = 1.0f - fy;  wyh[g] = fy;

            float xxv = rx1 + ((float)pw + ((float)g + 0.5f) * (1.0f / GRIDS)) * bsw;
            vx[g] = (xxv >= -1.0f) && (xxv <= (float)W);
            float xc = fmaxf(xxv, 0.0f);
            int lo2 = min((int)xc, W - 1);
            xlo[g] = lo2;
            xhi[g] = min(lo2 + 1, W - 1);
            float fx = (lo2 >= W - 1) ? 0.0f : (xc - (float)lo2);
            wxl[g] = 1.0f - fx;  wxh[g] = fx;
        }

        float acc = 0.0f;
#pragma unroll
        for (int gy = 0; gy < GRIDS; ++gy) {
#pragma unroll
            for (int gx = 0; gx < GRIDS; ++gx) {
                float v0 = pl[rowlo[gy] + xlo[gx]];
                float v1 = pl[rowlo[gy] + xhi[gx]];
                float v2 = pl[rowhi[gy] + xlo[gx]];
                float v3 = pl[rowhi[gy] + xhi[gx]];
                float w = (vy[gy] && vx[gx]) ? 0.25f : 0.0f;
                acc += w * (wyl[gy] * (wxl[gx] * v0 + wxh[gx] * v1)
                          + wyh[gy] * (wxl[gx] * v2 + wxh[gx] * v3));
            }
        }
        wsbuf[c_in * K + k] = acc;
    }
}

// ---- 64x64-tile transpose, float4 both global sides, 1024 threads (16 waves)
// per block, 256 blocks. Each thread: ONE float4 load + ONE float4 store.
// ws[c*K+k] -> out[k*C+c].  Requires K % 64 == 0; C edge guarded.
__global__ __launch_bounds__(NTHR) void transpose64_kernel(
    const float* __restrict__ wsbuf, float* __restrict__ out, int K)
{
    __shared__ float tile[64][65];
    int nkb = K >> 6;                        // 32 tiles along k
    int cb  = blockIdx.x / nkb;              // 8 tiles along c
    int kb  = blockIdx.x % nkb;
    int c0 = cb * 64, k0 = kb * 64;

    // load: kq = (t&15)*4 along k, cr = t>>4 along c (0..63)
    int kq = (threadIdx.x & 15) * 4;
    int cr = threadIdx.x >> 4;
    {
        int c = c0 + cr;
        float4 v = make_float4(0.f, 0.f, 0.f, 0.f);
        if (c < C) v = *(const float4*)(wsbuf + (size_t)c * K + k0 + kq);
        tile[cr][kq + 0] = v.x; tile[cr][kq + 1] = v.y;
        tile[cr][kq + 2] = v.z; tile[cr][kq + 3] = v.w;
    }
    __syncthreads();

    // store: cq = (t&15)*4 along c, kr = t>>4 along k (0..63)
    int cq = (threadIdx.x & 15) * 4;
    int kr = threadIdx.x >> 4;
    {
        int k = k0 + kr;
        int c = c0 + cq;
        float4 v;
        v.x = tile[cq + 0][kr];
        v.y = tile[cq + 1][kr];
        v.z = tile[cq + 2][kr];
        v.w = tile[cq + 3][kr];
        if (c + 3 < C) {
            *(float4*)(out + (size_t)k * C + c) = v;
        } else {
            if (c + 0 < C) out[(size_t)k * C + c + 0] = v.x;
            if (c + 1 < C) out[(size_t)k * C + c + 1] = v.y;
            if (c + 2 < C) out[(size_t)k * C + c + 2] = v.z;
            if (c + 3 < C) out[(size_t)k * C + c + 3] = v.w;
        }
    }
}

// ------------- fallback: direct-store kernel -------------
__global__ __launch_bounds__(256) void psroi_direct_kernel(
    const float* __restrict__ x, const float* __restrict__ rois,
    float* __restrict__ out, int K, int numKC)
{
    int bid  = blockIdx.x;
    int c_lo = bid & 7;
    int t    = bid >> 3;
    int kc   = t % numKC;
    int c_hi = t / numKC;
    int c_in = c_hi * 8 + c_lo;
    if (c_in >= C) return;
    int k = kc * 256 + (int)threadIdx.x;
    if (k >= K) return;

    int ph = (c_in / POOL) % POOL;
    int pw = c_in % POOL;
    const float* roi = rois + (size_t)k * 5;
    int   img = (int)roi[0];
    float rx1 = roi[1] * SCALE - 0.5f;
    float ry1 = roi[2] * SCALE - 0.5f;
    float rx2 = roi[3] * SCALE - 0.5f;
    float ry2 = roi[4] * SCALE - 0.5f;
    float bsh = (ry2 - ry1) * (1.0f / POOL);
    float bsw = (rx2 - rx1) * (1.0f / POOL);
    int off0 = (img * C + c_in) * PLANE;

    float acc = 0.0f;
#pragma unroll
    for (int gy = 0; gy < GRIDS; ++gy) {
        float yy = ry1 + ((float)ph + ((float)gy + 0.5f) * (1.0f / GRIDS)) * bsh;
        bool vy = (yy >= -1.0f) && (yy <= (float)H);
        float yc = fmaxf(yy, 0.0f);
        int lo = min((int)yc, H - 1);
        int rl = lo * W, rh = min(lo + 1, H - 1) * W;
        float fy = (lo >= H - 1) ? 0.0f : (yc - (float)lo);
#pragma unroll
        for (int gx = 0; gx < GRIDS; ++gx) {
            float xxv = rx1 + ((float)pw + ((float)gx + 0.5f) * (1.0f / GRIDS)) * bsw;
            bool vx = (xxv >= -1.0f) && (xxv <= (float)W);
            float xc = fmaxf(xxv, 0.0f);
            int lo2 = min((int)xc, W - 1);
            int xh = min(lo2 + 1, W - 1);
            float fx = (lo2 >= W - 1) ? 0.0f : (xc - (float)lo2);
            float w = (vy && vx) ? 0.25f : 0.0f;
            acc += w * ((1.0f - fy) * ((1.0f - fx) * x[off0 + rl + lo2] + fx * x[off0 + rl + xh])
                      + fy          * ((1.0f - fx) * x[off0 + rh + lo2] + fx * x[off0 + rh + xh]));
        }
    }
    out[k * C + c_in] = acc;
}

extern "C" void kernel_launch(void* const* d_in, const int* in_sizes, int n_in,
                              void* d_out, int out_size, void* d_ws, size_t ws_size,
                              hipStream_t stream) {
    const float* x    = (const float*)d_in[0];
    const float* rois = (const float*)d_in[1];
    float* out = (float*)d_out;
    int K = in_sizes[1] / 5;                              // 2048

    size_t wsbuf_bytes = (size_t)C * K * sizeof(float);   // 4,014,080

    if (ws_size >= wsbuf_bytes && (K % 64) == 0 && K <= NTHR * MAX_IT) {
        float* wsbuf = (float*)d_ws;
        int cGroups = (C + 7) / 8;                        // 62
        int blocks = cGroups * 2 * 8;                     // 992 (p interleaved mod 8)
        psroi_pair_kernel<<<blocks, NTHR, 0, stream>>>(x, rois, wsbuf, K);
        transpose64_kernel<<<8 * (K / 64), NTHR, 0, stream>>>(wsbuf, out, K);
    } else {
        int numKC = (K + 255) / 256;
        int blocks = ((C + 7) / 8) * numKC * 8;
        psroi_direct_kernel<<<blocks, 256, 0, stream>>>(x, rois, out, K, numKC);
    }
}